// Round 7
// baseline (248.408 us; speedup 1.0000x reference)
//
#include <hip/hip_runtime.h>
#include <hip/hip_fp16.h>

typedef _Float16 half8 __attribute__((ext_vector_type(8)));
typedef float f32x4 __attribute__((ext_vector_type(4)));

#define BB 32
#define NN 2048
#define DD 256
// Q pre-scale: (1/sqrt(D)=1/16) * log2(e), so softmax uses exp2 (raw v_exp_f32)
#define QS2 0.09016994374947424f

__device__ __forceinline__ void gload_lds16(const void* g, void* l) {
    __builtin_amdgcn_global_load_lds(
        (const __attribute__((address_space(1))) void*)g,
        (__attribute__((address_space(3))) void*)l, 16, 0, 0);
}

// ---- P1: blocks 0..511: Wt[mat][c][k] = W[k][c] f16 (coalesced reads).
//          blocks 512..576: wv[d] = Wv[d,:].Ww ; wv[256] = bv.Ww + bw
__global__ void k_pre(const float* __restrict__ Wq, const float* __restrict__ Wk,
                      const float* __restrict__ Wv, const float* __restrict__ bv,
                      const float* __restrict__ Ww, const float* __restrict__ bw,
                      _Float16* __restrict__ Wt, float* __restrict__ wv) {
    if (blockIdx.x < 512) {
        int idx = blockIdx.x * 256 + threadIdx.x;  // 131072
        int mat = idx >> 16;
        int r = (idx >> 8) & 255;
        int c = idx & 255;
        const float* W = mat ? Wk : Wq;
        Wt[mat * 65536 + c * 256 + r] = (_Float16)W[r * 256 + c];
    } else {
        int gw = ((blockIdx.x - 512) * 256 + (int)threadIdx.x) >> 6;
        int lane = threadIdx.x & 63;
        if (gw > 256) return;
        const float* row = (gw < 256) ? (Wv + gw * 256) : bv;
        f32x4 a = *((const f32x4*)row + lane);
        f32x4 wk = *((const f32x4*)Ww + lane);
        float p = a[0] * wk[0] + a[1] * wk[1] + a[2] * wk[2] + a[3] * wk[3];
        #pragma unroll
        for (int m = 1; m < 64; m <<= 1) p += __shfl_xor(p, m, 64);
        if (lane == 0) wv[gw] = (gw < 256) ? p : (p + bw[0]);
    }
}

// ---- K1: Q and K projection GEMM + fused S = x.wv + cst.
// Q output pre-scaled by QS2 (folds softmax scale AND log2(e) into Q).
__global__ __launch_bounds__(512, 2) void k_proj(
    const float* __restrict__ x, const _Float16* __restrict__ Wt,
    const float* __restrict__ bq, const float* __restrict__ bk,
    const float* __restrict__ wv,
    _Float16* __restrict__ Qh, _Float16* __restrict__ Kh, float* __restrict__ S) {
    __shared__ _Float16 As[128][40];  // 32 k-cols + 8 pad
    int m0 = blockIdx.x * 128;
    int tid = threadIdx.x, w = tid >> 6, l = tid & 63;
    int wr = w >> 2, wc = w & 3;
    int srow = tid >> 2, sc8 = (tid & 3) * 8;
    int lr = l & 15, lg = l >> 4;
    int acol = lg * 8;
    float sacc = 0.f;

    f32x4 zz = {0.f, 0.f, 0.f, 0.f};
    f32x4 acc[2][4][4];
    #pragma unroll
    for (int m = 0; m < 2; ++m)
        #pragma unroll
        for (int i = 0; i < 4; ++i)
            #pragma unroll
            for (int j = 0; j < 4; ++j) acc[m][i][j] = zz;

    for (int k0 = 0; k0 < DD; k0 += 32) {
        __syncthreads();
        {   // stage 128x32 of x f32->f16; fold partial S-dot in f32
            const float* src = x + (long)(m0 + srow) * DD + k0 + sc8;
            f32x4 a = *(const f32x4*)src;
            f32x4 b = *(const f32x4*)(src + 4);
            f32x4 wa = *(const f32x4*)(wv + k0 + sc8);
            f32x4 wb = *(const f32x4*)(wv + k0 + sc8 + 4);
            sacc += a[0] * wa[0] + a[1] * wa[1] + a[2] * wa[2] + a[3] * wa[3]
                  + b[0] * wb[0] + b[1] * wb[1] + b[2] * wb[2] + b[3] * wb[3];
            half8 h;
            h[0] = (_Float16)a[0]; h[1] = (_Float16)a[1];
            h[2] = (_Float16)a[2]; h[3] = (_Float16)a[3];
            h[4] = (_Float16)b[0]; h[5] = (_Float16)b[1];
            h[6] = (_Float16)b[2]; h[7] = (_Float16)b[3];
            *(half8*)&As[srow][sc8] = h;
        }
        __syncthreads();
        half8 af[4];
        #pragma unroll
        for (int rt = 0; rt < 4; ++rt)
            af[rt] = *(const half8*)&As[wr * 64 + rt * 16 + lr][acol];
        #pragma unroll
        for (int mat = 0; mat < 2; ++mat)
            #pragma unroll
            for (int ct = 0; ct < 4; ++ct) {
                half8 bf = *(const half8*)(Wt + mat * 65536 +
                                           (long)(wc * 64 + ct * 16 + lr) * DD + k0 + acol);
                #pragma unroll
                for (int rt = 0; rt < 4; ++rt)
                    acc[mat][rt][ct] =
                        __builtin_amdgcn_mfma_f32_16x16x32_f16(af[rt], bf, acc[mat][rt][ct], 0, 0, 0);
            }
    }
    // S: reduce 4 quarter-sums (lanes differing in bits 0-1, same wave)
    sacc += __shfl_xor(sacc, 1, 64);
    sacc += __shfl_xor(sacc, 2, 64);
    if ((tid & 3) == 0) S[m0 + srow] = sacc + wv[DD];

    #pragma unroll
    for (int mat = 0; mat < 2; ++mat) {
        const float* bias = mat ? bk : bq;
        _Float16* Out = mat ? Kh : Qh;
        float osc = mat ? 1.0f : QS2;
        #pragma unroll
        for (int ct = 0; ct < 4; ++ct) {
            int col = wc * 64 + ct * 16 + lr;
            float bi = bias[col];
            #pragma unroll
            for (int rt = 0; rt < 4; ++rt)
                #pragma unroll
                for (int r = 0; r < 4; ++r) {
                    int row = m0 + wr * 64 + rt * 16 + lg * 4 + r;
                    Out[(long)row * DD + col] = (_Float16)((acc[mat][rt][ct][r] + bi) * osc);
                }
        }
    }
}

// ---- K2: out[b,n] = sum_m softmax(QK^T/16)[n,m] * S[b,m]
// 16 waves (4/SIMD), 32 q-rows/wave, m-range halved across wave groups
// (grp = w>>3). LDS traffic halved vs full-range AND 4 waves/SIMD for
// cross-wave MFMA/VALU/LDS overlap. setprio(1) around the MFMA cluster.
__global__ __launch_bounds__(1024, 4) void k_flash(
    const _Float16* __restrict__ Qh, const _Float16* __restrict__ Kh,
    const float* __restrict__ S, float* __restrict__ out) {
    __shared__ _Float16 Ks[2][2][64][256];  // [dbuf][grp][row][col] 128 KB
    __shared__ float Ss[2048];              // 8 KB (whole batch S row)
    __shared__ float zred[8][64][8];        // 16 KB merge buffer
    int u = blockIdx.x;
    int b = (u & 7) | (((u >> 3) & 3) << 3);  // batch pinned to XCD b%8
    int q0 = (u >> 5) * 256;
    const _Float16* Qb = Qh + (long)b * NN * DD;
    const _Float16* Kb = Kh + (long)b * NN * DD;
    const float* Sb = S + b * NN;
    int tid = threadIdx.x, w = tid >> 6, l = tid & 63;
    int lr = l & 15, lg = l >> 4;
    int l5 = l >> 5, c32 = l & 31;
    int qs = w & 7, grp = w >> 3;
    int mbase = grp * 1024;

    // q fragments: 32 rows/wave, pre-scaled by QS2 in k_proj
    half8 qf[2][8];
    #pragma unroll
    for (int qa = 0; qa < 2; ++qa)
        #pragma unroll
        for (int kk = 0; kk < 8; ++kk)
            qf[qa][kk] = *(const half8*)(Qb + (long)(q0 + qs * 32 + qa * 16 + lr) * DD + kk * 32 + lg * 8);

    // stage S (8 KB) via DMA: first 8 waves, wave-uniform dest + lane*16
    if (w < 8) gload_lds16(Sb + tid * 4, &Ss[(tid & ~63) * 4]);

    // stage K step 0: wave stages 8 rows of its group's 64-row tile
    #pragma unroll
    for (int i = 0; i < 4; ++i) {
        int r0 = qs * 8 + i * 2;
        int r = r0 + l5;
        gload_lds16(Kb + (long)(mbase + r) * DD + ((c32 ^ (r & 7)) * 8), &Ks[0][grp][r0][0]);
    }
    asm volatile("s_waitcnt vmcnt(0)" ::: "memory");
    __syncthreads();

    float z[2] = {0.f, 0.f}, y[2] = {0.f, 0.f};
    int cur = 0;
    for (int t = 0; t < 16; ++t) {
        if (t < 15) {  // prefetch next step into buf^1
            #pragma unroll
            for (int i = 0; i < 4; ++i) {
                int r0 = qs * 8 + i * 2;
                int r = r0 + l5;
                gload_lds16(Kb + (long)(mbase + (t + 1) * 64 + r) * DD + ((c32 ^ (r & 7)) * 8),
                            &Ks[cur ^ 1][grp][r0][0]);
            }
        }
        // ct-major: exp of ct overlaps MFMA of ct+1 (and other waves' phases)
        #pragma unroll
        for (int ct = 0; ct < 4; ++ct) {
            f32x4 zz = {0.f, 0.f, 0.f, 0.f};
            f32x4 a[2] = {zz, zz};
            __builtin_amdgcn_s_setprio(1);
            #pragma unroll
            for (int kk = 0; kk < 8; ++kk) {
                half8 kf = *(const half8*)&Ks[cur][grp][ct * 16 + lr][((kk * 4 + lg) ^ (lr & 7)) * 8];
                #pragma unroll
                for (int qa = 0; qa < 2; ++qa)
                    a[qa] = __builtin_amdgcn_mfma_f32_16x16x32_f16(kf, qf[qa][kk], a[qa], 0, 0, 0);
            }
            __builtin_amdgcn_s_setprio(0);
            f32x4 sv = *(const f32x4*)&Ss[mbase + t * 64 + ct * 16 + lg * 4];
            #pragma unroll
            for (int qa = 0; qa < 2; ++qa)
                #pragma unroll
                for (int r = 0; r < 4; ++r) {
                    float e = __builtin_exp2f(a[qa][r]);  // Q pre-scaled by 1/16*log2e
                    z[qa] += e;
                    y[qa] = fmaf(e, sv[r], y[qa]);
                }
        }
        asm volatile("s_waitcnt vmcnt(0)" ::: "memory");
        __syncthreads();
        cur ^= 1;
    }
    // merge the two m-halves: grp1 deposits, grp0 combines
    if (grp == 1) {
        #pragma unroll
        for (int qa = 0; qa < 2; ++qa) {
            zred[qs][l][qa] = z[qa];
            zred[qs][l][qa + 4] = y[qa];
        }
    }
    __syncthreads();
    if (grp == 0) {
        #pragma unroll
        for (int qa = 0; qa < 2; ++qa) {
            z[qa] += zred[qs][l][qa];
            y[qa] += zred[qs][l][qa + 4];
            y[qa] += __shfl_xor(y[qa], 16, 64);
            y[qa] += __shfl_xor(y[qa], 32, 64);
            z[qa] += __shfl_xor(z[qa], 16, 64);
            z[qa] += __shfl_xor(z[qa], 32, 64);
        }
        if (l < 16)
            #pragma unroll
            for (int qa = 0; qa < 2; ++qa)
                out[b * NN + q0 + qs * 32 + qa * 16 + lr] = y[qa] / z[qa];
    }
}

extern "C" void kernel_launch(void* const* d_in, const int* in_sizes, int n_in,
                              void* d_out, int out_size, void* d_ws, size_t ws_size,
                              hipStream_t stream) {
    const float* x  = (const float*)d_in[0];
    const float* Wq = (const float*)d_in[1];
    const float* bq = (const float*)d_in[2];
    const float* Wk = (const float*)d_in[3];
    const float* bk = (const float*)d_in[4];
    const float* Wv = (const float*)d_in[5];
    const float* bv = (const float*)d_in[6];
    const float* Ww = (const float*)d_in[7];
    const float* bw = (const float*)d_in[8];
    char* ws = (char*)d_ws;
    // workspace layout: Qh 32MB | Kh 32MB | Wt 256KB | S 256KB | wv 4KB
    _Float16* Qh = (_Float16*)(ws);
    _Float16* Kh = (_Float16*)(ws + 33554432);
    _Float16* Wt = (_Float16*)(ws + 67108864);
    float* S     = (float*)(ws + 67108864 + 262144);
    float* wv    = (float*)(ws + 67108864 + 262144 + 262144);
    float* outp  = (float*)d_out;

    k_pre<<<dim3(577), dim3(256), 0, stream>>>(Wq, Wk, Wv, bv, Ww, bw, Wt, wv);
    k_proj<<<dim3(512), dim3(512), 0, stream>>>(x, Wt, bq, bk, wv, Qh, Kh, S);
    k_flash<<<dim3(256), dim3(1024), 0, stream>>>(Qh, Kh, S, outp);
}

// Round 11
// 221.517 us; speedup vs baseline: 1.1214x; 1.1214x over previous
//
#include <hip/hip_runtime.h>
#include <hip/hip_fp16.h>

typedef _Float16 half8 __attribute__((ext_vector_type(8)));
typedef float f32x4 __attribute__((ext_vector_type(4)));

#define BB 32
#define NN 2048
#define DD 256
#define SCALE 0.0625f

__device__ __forceinline__ void gload_lds16(const void* g, void* l) {
    __builtin_amdgcn_global_load_lds(
        (const __attribute__((address_space(1))) void*)g,
        (__attribute__((address_space(3))) void*)l, 16, 0, 0);
}

// ---- P1: blocks 0..511: Wt[mat][c][k] = W[k][c] f16 (coalesced reads).
//          blocks 512..576: wv[d] = Wv[d,:].Ww ; wv[256] = bv.Ww + bw
__global__ void k_pre(const float* __restrict__ Wq, const float* __restrict__ Wk,
                      const float* __restrict__ Wv, const float* __restrict__ bv,
                      const float* __restrict__ Ww, const float* __restrict__ bw,
                      _Float16* __restrict__ Wt, float* __restrict__ wv) {
    if (blockIdx.x < 512) {
        int idx = blockIdx.x * 256 + threadIdx.x;  // 131072
        int mat = idx >> 16;
        int r = (idx >> 8) & 255;
        int c = idx & 255;
        const float* W = mat ? Wk : Wq;
        Wt[mat * 65536 + c * 256 + r] = (_Float16)W[r * 256 + c];
    } else {
        int gw = ((blockIdx.x - 512) * 256 + (int)threadIdx.x) >> 6;
        int lane = threadIdx.x & 63;
        if (gw > 256) return;
        const float* row = (gw < 256) ? (Wv + gw * 256) : bv;
        f32x4 a = *((const f32x4*)row + lane);
        f32x4 wk = *((const f32x4*)Ww + lane);
        float p = a[0] * wk[0] + a[1] * wk[1] + a[2] * wk[2] + a[3] * wk[3];
        #pragma unroll
        for (int m = 1; m < 64; m <<= 1) p += __shfl_xor(p, m, 64);
        if (lane == 0) wv[gw] = (gw < 256) ? p : (p + bw[0]);
    }
}

// ---- K1: projection GEMM, ONE matrix per block (blockIdx.y = mat).
// acc halves to 64 VGPRs -> ~120 VGPR total -> 2 blocks/CU (4 waves/SIMD),
// independent barriers overlap staging with MFMA. Math per output identical
// to the verified R3 kernel. S (= x.wv + cst) computed by mat==0 blocks.
__global__ __launch_bounds__(512, 2) void k_proj(
    const float* __restrict__ x, const _Float16* __restrict__ Wt,
    const float* __restrict__ bq, const float* __restrict__ bk,
    const float* __restrict__ wv,
    _Float16* __restrict__ Qh, _Float16* __restrict__ Kh, float* __restrict__ S) {
    __shared__ _Float16 As[128][40];  // 32 k-cols + 8 pad
    int m0 = blockIdx.x * 128;
    int mat = blockIdx.y;
    const _Float16* Wm = Wt + mat * 65536;
    int tid = threadIdx.x, w = tid >> 6, l = tid & 63;
    int wr = w >> 2, wc = w & 3;
    int srow = tid >> 2, sc8 = (tid & 3) * 8;
    int lr = l & 15, lg = l >> 4;
    int acol = lg * 8;
    float sacc = 0.f;

    f32x4 zz = {0.f, 0.f, 0.f, 0.f};
    f32x4 acc[4][4];
    #pragma unroll
    for (int i = 0; i < 4; ++i)
        #pragma unroll
        for (int j = 0; j < 4; ++j) acc[i][j] = zz;

    for (int k0 = 0; k0 < DD; k0 += 32) {
        __syncthreads();
        {   // stage 128x32 of x f32->f16; fold partial S-dot in f32
            const float* src = x + (long)(m0 + srow) * DD + k0 + sc8;
            f32x4 a = *(const f32x4*)src;
            f32x4 b = *(const f32x4*)(src + 4);
            f32x4 wa = *(const f32x4*)(wv + k0 + sc8);
            f32x4 wb = *(const f32x4*)(wv + k0 + sc8 + 4);
            sacc += a[0] * wa[0] + a[1] * wa[1] + a[2] * wa[2] + a[3] * wa[3]
                  + b[0] * wb[0] + b[1] * wb[1] + b[2] * wb[2] + b[3] * wb[3];
            half8 h;
            h[0] = (_Float16)a[0]; h[1] = (_Float16)a[1];
            h[2] = (_Float16)a[2]; h[3] = (_Float16)a[3];
            h[4] = (_Float16)b[0]; h[5] = (_Float16)b[1];
            h[6] = (_Float16)b[2]; h[7] = (_Float16)b[3];
            *(half8*)&As[srow][sc8] = h;
        }
        __syncthreads();
        half8 af[4];
        #pragma unroll
        for (int rt = 0; rt < 4; ++rt)
            af[rt] = *(const half8*)&As[wr * 64 + rt * 16 + lr][acol];
        #pragma unroll
        for (int ct = 0; ct < 4; ++ct) {
            half8 bf = *(const half8*)(Wm + (long)(wc * 64 + ct * 16 + lr) * DD + k0 + acol);
            #pragma unroll
            for (int rt = 0; rt < 4; ++rt)
                acc[rt][ct] =
                    __builtin_amdgcn_mfma_f32_16x16x32_f16(af[rt], bf, acc[rt][ct], 0, 0, 0);
        }
    }
    // S: reduce 4 quarter-sums (lanes differing in bits 0-1, same wave)
    if (mat == 0) {
        sacc += __shfl_xor(sacc, 1, 64);
        sacc += __shfl_xor(sacc, 2, 64);
        if ((tid & 3) == 0) S[m0 + srow] = sacc + wv[DD];
    }

    const float* bias = mat ? bk : bq;
    _Float16* Out = mat ? Kh : Qh;
    #pragma unroll
    for (int ct = 0; ct < 4; ++ct) {
        int col = wc * 64 + ct * 16 + lr;
        float bi = bias[col];
        #pragma unroll
        for (int rt = 0; rt < 4; ++rt)
            #pragma unroll
            for (int r = 0; r < 4; ++r) {
                int row = m0 + wr * 64 + rt * 16 + lg * 4 + r;
                Out[(long)row * DD + col] = (_Float16)(acc[rt][ct][r] + bi);
            }
    }
}

// ---- K2: out[b,n] = sum_m softmax(QK^T/16)[n,m] * S[b,m]
// EXACT R3 version (verified 77 us, absmax 1.953e-3): 512 threads = 8 waves
// (2/SIMD), 32 q-rows/wave, 256 q-rows/block, grid 256, batch-clustered XCD.
// Double-buffered 64-row K tile via global_load_lds, chunk^row&7 XOR swizzle.
__global__ __launch_bounds__(512, 2) void k_flash(
    const _Float16* __restrict__ Qh, const _Float16* __restrict__ Kh,
    const float* __restrict__ S, float* __restrict__ out) {
    __shared__ _Float16 Ks[2][64][256];  // 64 KB double buffer
    int u = blockIdx.x;
    int b = (u & 7) | (((u >> 3) & 3) << 3);  // u%8 -> XCD; batch pinned to XCD b%8
    int q0 = (u >> 5) * 256;
    const _Float16* Qb = Qh + (long)b * NN * DD;
    const _Float16* Kb = Kh + (long)b * NN * DD;
    const float* Sb = S + b * NN;
    int tid = threadIdx.x, w = tid >> 6, l = tid & 63;
    int lr = l & 15, lg = l >> 4;
    int l5 = l >> 5, c32 = l & 31;

    half8 qf[2][8];
    #pragma unroll
    for (int qa = 0; qa < 2; ++qa)
        #pragma unroll
        for (int kk = 0; kk < 8; ++kk)
            qf[qa][kk] = *(const half8*)(Qb + (long)(q0 + w * 32 + qa * 16 + lr) * DD + kk * 32 + lg * 8);

    float z[2] = {0.f, 0.f}, y[2] = {0.f, 0.f};

    // prologue: stage tile 0 into buf 0 (wave w stages rows w*8..w*8+7)
    #pragma unroll
    for (int i = 0; i < 4; ++i) {
        int rt = w * 8 + i * 2 + l5;
        gload_lds16(Kb + (long)rt * DD + ((c32 ^ (rt & 7)) * 8), &Ks[0][w * 8 + i * 2][0]);
    }
    asm volatile("s_waitcnt vmcnt(0)" ::: "memory");
    __syncthreads();

    int cur = 0;
    for (int t = 0; t < 32; ++t) {
        int m0 = t * 64;
        if (t < 31) {  // prefetch next tile into buf^1
            #pragma unroll
            for (int i = 0; i < 4; ++i) {
                int rt = w * 8 + i * 2 + l5;
                gload_lds16(Kb + (long)(m0 + 64 + rt) * DD + ((c32 ^ (rt & 7)) * 8),
                            &Ks[cur ^ 1][w * 8 + i * 2][0]);
            }
        }
        // issue S loads early; consumed after MFMA section (latency hidden)
        f32x4 sv[4];
        #pragma unroll
        for (int ct = 0; ct < 4; ++ct)
            sv[ct] = *(const f32x4*)(Sb + m0 + ct * 16 + lg * 4);

        f32x4 zz = {0.f, 0.f, 0.f, 0.f};
        f32x4 acc[2][4];
        #pragma unroll
        for (int qa = 0; qa < 2; ++qa)
            #pragma unroll
            for (int ct = 0; ct < 4; ++ct) acc[qa][ct] = zz;

        #pragma unroll
        for (int kk = 0; kk < 8; ++kk) {
            int pc = ((kk * 4 + lg) ^ (lr & 7)) * 8;
            half8 kf[4];
            #pragma unroll
            for (int ct = 0; ct < 4; ++ct)
                kf[ct] = *(const half8*)&Ks[cur][ct * 16 + lr][pc];
            #pragma unroll
            for (int ct = 0; ct < 4; ++ct)
                #pragma unroll
                for (int qa = 0; qa < 2; ++qa)
                    acc[qa][ct] = __builtin_amdgcn_mfma_f32_16x16x32_f16(kf[ct], qf[qa][kk], acc[qa][ct], 0, 0, 0);
        }
        #pragma unroll
        for (int ct = 0; ct < 4; ++ct)
            #pragma unroll
            for (int qa = 0; qa < 2; ++qa)
                #pragma unroll
                for (int r = 0; r < 4; ++r) {
                    float e = __expf(acc[qa][ct][r] * SCALE);
                    z[qa] += e;
                    y[qa] = fmaf(e, sv[ct][r], y[qa]);
                }
        asm volatile("s_waitcnt vmcnt(0)" ::: "memory");
        __syncthreads();
        cur ^= 1;
    }
    #pragma unroll
    for (int qa = 0; qa < 2; ++qa) {
        y[qa] += __shfl_xor(y[qa], 16, 64);
        y[qa] += __shfl_xor(y[qa], 32, 64);
        z[qa] += __shfl_xor(z[qa], 16, 64);
        z[qa] += __shfl_xor(z[qa], 32, 64);
    }
    if (l < 16)
        #pragma unroll
        for (int qa = 0; qa < 2; ++qa)
            out[b * NN + q0 + w * 32 + qa * 16 + lr] = y[qa] / z[qa];
}

extern "C" void kernel_launch(void* const* d_in, const int* in_sizes, int n_in,
                              void* d_out, int out_size, void* d_ws, size_t ws_size,
                              hipStream_t stream) {
    const float* x  = (const float*)d_in[0];
    const float* Wq = (const float*)d_in[1];
    const float* bq = (const float*)d_in[2];
    const float* Wk = (const float*)d_in[3];
    const float* bk = (const float*)d_in[4];
    const float* Wv = (const float*)d_in[5];
    const float* bv = (const float*)d_in[6];
    const float* Ww = (const float*)d_in[7];
    const float* bw = (const float*)d_in[8];
    char* ws = (char*)d_ws;
    // workspace layout: Qh 32MB | Kh 32MB | Wt 256KB | S 256KB | wv 4KB
    _Float16* Qh = (_Float16*)(ws);
    _Float16* Kh = (_Float16*)(ws + 33554432);
    _Float16* Wt = (_Float16*)(ws + 67108864);
    float* S     = (float*)(ws + 67108864 + 262144);
    float* wv    = (float*)(ws + 67108864 + 262144 + 262144);
    float* outp  = (float*)d_out;

    k_pre<<<dim3(577), dim3(256), 0, stream>>>(Wq, Wk, Wv, bv, Ww, bw, Wt, wv);
    k_proj<<<dim3(512, 2), dim3(512), 0, stream>>>(x, Wt, bq, bk, wv, Qh, Kh, S);
    k_flash<<<dim3(256), dim3(512), 0, stream>>>(Qh, Kh, S, outp);
}